// Round 7
// baseline (246.555 us; speedup 1.0000x reference)
//
#include <hip/hip_runtime.h>
#include <hip/hip_bf16.h>

#define BB 4
#define TT 4096
#define CC 1024
#define HH 64

typedef _Float16 f16;
typedef __attribute__((ext_vector_type(8))) _Float16 f16x8;
typedef __attribute__((ext_vector_type(4))) _Float16 f16x4;
typedef __attribute__((ext_vector_type(4))) float f32x4;

#define MFMA32(a,b,c) __builtin_amdgcn_mfma_f32_16x16x32_f16((a),(b),(c),0,0,0)
#define MFMA16(a,b,c) __builtin_amdgcn_mfma_f32_16x16x16f16((a),(b),(c),0,0,0)

// frag-major sizes (f16 units)
#define WF_ELEMS (3 * 32 * 4 * 64 * 8)        // 196,608
#define CHUNK_F16 1024                        // per 16-row chunk: 2 halves x 64 lanes x 8
#define PB_F16 (256 * CHUNK_F16)              // per batch: 256 chunks

// Async global->LDS, 16B per lane; LDS dest wave-uniform + lane*16.
static __device__ __forceinline__ void gl_lds16(const void* g, void* l) {
  __builtin_amdgcn_global_load_lds(
      (const __attribute__((address_space(1))) unsigned int*)g,
      (__attribute__((address_space(3))) unsigned int*)l, 16, 0, 0);
}

static __device__ __forceinline__ f16x8 pack2(f32x4 a, f32x4 b) {
  f16x8 r;
  r[0]=(f16)a[0]; r[1]=(f16)a[1]; r[2]=(f16)a[2]; r[3]=(f16)a[3];
  r[4]=(f16)b[0]; r[5]=(f16)b[1]; r[6]=(f16)b[2]; r[7]=(f16)b[3];
  return r;
}

// ---------------------------------------------------------------------------
// Repack W -> frag-major f16; softmax double-scale log2(e)/64 folded into Wq.
// ---------------------------------------------------------------------------
__global__ __launch_bounds__(64) void wrepack_kernel(
    const float* __restrict__ Wqg, const float* __restrict__ Wkg,
    const float* __restrict__ Wvg, f16* __restrict__ Wf)
{
  const int bx = blockIdx.x;
  const int nt = bx & 3;
  const int kc = (bx >> 2) & 31;
  const int p  = bx >> 7;
  const float* W = (p == 0) ? Wqg : (p == 1) ? Wkg : Wvg;
  const float sc = (p == 0) ? (1.4426950408889634f / 64.0f) : 1.0f;

  const int lane = threadIdx.x;
  const int l16 = lane & 15, quad = lane >> 4;
  const float* src = W + (size_t)(nt * 16 + l16) * CC + kc * 32 + quad * 8;
  f32x4 a = *(const f32x4*)src;
  f32x4 b = *(const f32x4*)(src + 4);
  f16x8 r;
  #pragma unroll
  for (int j = 0; j < 4; ++j) { r[j] = (f16)(a[j] * sc); r[j + 4] = (f16)(b[j] * sc); }
  *(f16x8*)(Wf + (size_t)bx * 512 + lane * 8) = r;
}

// ---------------------------------------------------------------------------
// Projection: 128-row tiles, 512 threads (8 waves), grid (128,3).
// Halves per-chip W re-staging traffic vs 64-row tiles (49 MB vs 98 MB).
// Double-buffered async staging: X 32 KB/iter, W 8 KB/iter. LDS 80 KB ->
// 2 blocks/CU, 16 waves/CU.
// ---------------------------------------------------------------------------
__global__ __launch_bounds__(512) void proj_kernel(
    const float* __restrict__ qg, const float* __restrict__ kg, const float* __restrict__ vg,
    const f16* __restrict__ Wf,
    f16* __restrict__ Qf, f16* __restrict__ Kf, f16* __restrict__ Vf)
{
  __shared__ float Xs[2][128][64];    // 64 KB
  __shared__ f16   Ws[2][8][64][8];   // 16 KB

  const float* X; f16* O; const int p = blockIdx.y;
  if (p == 0)      { X = qg; O = Qf; }
  else if (p == 1) { X = kg; O = Kf; }
  else             { X = vg; O = Vf; }

  const int tid  = threadIdx.x;
  const int w    = tid >> 6;          // 0..7
  const int lane = tid & 63;
  const int quad = lane >> 4;
  const int l16  = lane & 15;
  const int r0   = blockIdx.x * 128;

  // X staging: wave w, inst s covers rows R = w*16+s*4+(lane>>4); stored
  // phys chunk (lane&15) holds logical chunk lc = (lane&15)^((R&7)<<1).
  const float* Xrow[4];
  #pragma unroll
  for (int s = 0; s < 4; ++s) {
    const int R  = w * 16 + s * 4 + (lane >> 4);
    const int lc = (lane & 15) ^ ((R & 7) << 1);
    Xrow[s] = X + (size_t)(r0 + R) * CC + lc * 4;
  }
  // W staging: one inst per wave covers frag-block (it*8 + w).
  const f16* Wfp = Wf + (size_t)p * 128 * 512;
  const f16* Wsrc = Wfp + (size_t)w * 512 + lane * 8;

  f32x4 acc[4];
  #pragma unroll
  for (int nt = 0; nt < 4; ++nt) acc[nt] = (f32x4){0.f, 0.f, 0.f, 0.f};

  // initial stage -> buf 0
  #pragma unroll
  for (int s = 0; s < 4; ++s)
    gl_lds16(Xrow[s], &Xs[0][w * 16 + s * 4][0]);
  gl_lds16(Wsrc, &Ws[0][w][0][0]);

  const int sw = (l16 & 7) << 1;   // frag-read swizzle (row w*16+l16 -> R&7 = l16&7)

  for (int it = 0; it < 16; ++it) {
    const int buf = it & 1;
    __syncthreads();   // vmcnt(0) drains staging of buf
    if (it < 15) {
      #pragma unroll
      for (int s = 0; s < 4; ++s)
        gl_lds16(Xrow[s] + (it + 1) * 64, &Xs[buf ^ 1][w * 16 + s * 4][0]);
      gl_lds16(Wsrc + (size_t)(it + 1) * 4096, &Ws[buf ^ 1][w][0][0]);
    }
    #pragma unroll
    for (int kk = 0; kk < 2; ++kk) {
      const int c0 = kk * 8 + quad * 2;
      f32x4 a0 = *(const f32x4*)&Xs[buf][w * 16 + l16][(c0 ^ sw) * 4];
      f32x4 a1 = *(const f32x4*)&Xs[buf][w * 16 + l16][((c0 + 1) ^ sw) * 4];
      f16x8 af = pack2(a0, a1);
      #pragma unroll
      for (int nt = 0; nt < 4; ++nt) {
        f16x8 bf = *(const f16x8*)&Ws[buf][kk * 4 + nt][lane][0];
        acc[nt] = MFMA32(af, bf, acc[nt]);
      }
    }
  }

  // epilogue: C-layout acc -> frag-major via wave-private LDS scratch.
  // Xs[0] rows w*16..w*16+15 (4 KB/wave): last read by this wave at it=14,
  // already ordered before it=15's barrier. Wave-private -> no extra barrier.
  f16 (*Ls)[66] = (f16(*)[66])&Xs[0][w * 16][0];
  #pragma unroll
  for (int nt = 0; nt < 4; ++nt)
    #pragma unroll
    for (int r = 0; r < 4; ++r)
      Ls[quad * 4 + r][nt * 16 + l16] = (f16)acc[nt][r];
  const size_t chunk = (size_t)blockIdx.x * 8 + w;
  if (p < 2) {
    // Q/K frag: [chunk][half][lane][8] = tile[row=l16][hd=32h+8q+j]
    #pragma unroll
    for (int h = 0; h < 2; ++h) {
      f16x8 t = *(const f16x8*)&Ls[l16][h * 32 + quad * 8];
      *(f16x8*)(O + (chunk * 2 + h) * 512 + lane * 8) = t;
    }
  } else {
    // V frag: [chunk][np][lane][8] = tile[key=4q+(j&3)][hd=(2np+(j>>2))*16+l16]
    #pragma unroll
    for (int np = 0; np < 2; ++np) {
      f16x8 t;
      #pragma unroll
      for (int j = 0; j < 8; ++j)
        t[j] = Ls[quad * 4 + (j & 3)][(2 * np + (j >> 2)) * 16 + l16];
      *(f16x8*)(O + (chunk * 2 + np) * 512 + lane * 8) = t;
    }
  }
}

// ---------------------------------------------------------------------------
// Flash attention, mask s <= t+1. Fold-pair (j1, j2=63-j1) processed in ONE
// loop over the merged key range [0, n2): each staged K/V step serves both
// tiles (two accumulator sets per wave) -> staged bytes = sum(n2) not
// sum(n1+n2). S-way split slices [0, n2). Frag-major -> all staging is
// contiguous 8 KB; frag reads lane-linear ds_read_b128.
// ---------------------------------------------------------------------------
__global__ __launch_bounds__(256) void attn_kernel(
    const f16* __restrict__ Qf, const f16* __restrict__ Kf, const f16* __restrict__ Vf,
    float* __restrict__ Opart, float* __restrict__ lpart, int S)
{
  __shared__ f16 Ks[2][8][64][8];   // 16 KB
  __shared__ f16 Vs[2][8][64][8];   // 16 KB

  const int pr = blockIdx.x;   // fold pair 0..31
  const int sp = blockIdx.y;   // key split 0..S-1
  const int b  = blockIdx.z;
  const int tid  = threadIdx.x;
  const int wave = tid >> 6;
  const int lane = tid & 63;
  const int quad = lane >> 4;
  const int l16  = lane & 15;

  const int j1 = pr, j2 = 63 - pr;
  const int n2 = min(j2 + 2, 64);          // merged staging range [0, n2)
  const int lo = n2 * sp / S, hi = n2 * (sp + 1) / S;

  const int m1 = j1 * 64 + wave * 16;
  const int m2 = j2 * 64 + wave * 16;
  // wave-level compute bounds (tile active while s0 <= m+16)
  const int e1 = min(hi, j1 + 1 + (wave == 3 ? 1 : 0));
  const int e2 = min(hi, j2 + 1 + (wave == 3 ? 1 : 0));

  const f16* Qfb = Qf + (size_t)b * PB_F16;
  const f16* Kfb = Kf + (size_t)b * PB_F16;
  const f16* Vfb = Vf + (size_t)b * PB_F16;

  f16x8 qa10 = *(const f16x8*)(Qfb + ((size_t)(m1 >> 4) * 2 + 0) * 512 + lane * 8);
  f16x8 qa11 = *(const f16x8*)(Qfb + ((size_t)(m1 >> 4) * 2 + 1) * 512 + lane * 8);
  f16x8 qa20 = *(const f16x8*)(Qfb + ((size_t)(m2 >> 4) * 2 + 0) * 512 + lane * 8);
  f16x8 qa21 = *(const f16x8*)(Qfb + ((size_t)(m2 >> 4) * 2 + 1) * 512 + lane * 8);

  f32x4 o1[4], o2[4];
  float ls1 = 0.f, ls2 = 0.f;
  #pragma unroll
  for (int nt = 0; nt < 4; ++nt) {
    o1[nt] = (f32x4){0.f, 0.f, 0.f, 0.f};
    o2[nt] = (f32x4){0.f, 0.f, 0.f, 0.f};
  }

  if (lo < hi) {
    const int idx = 2 * wave;
    #pragma unroll
    for (int jj = 0; jj < 2; ++jj) {
      gl_lds16(Kfb + (size_t)lo * 4096 + (idx + jj) * 512 + lane * 8, &Ks[0][idx + jj][0][0]);
      gl_lds16(Vfb + (size_t)lo * 4096 + (idx + jj) * 512 + lane * 8, &Vs[0][idx + jj][0][0]);
    }
  }

  for (int st = lo; st < hi; ++st) {
    const int buf = (st - lo) & 1;
    __syncthreads();   // drains staging of buf
    if (st + 1 < hi) {
      const int idx = 2 * wave;
      #pragma unroll
      for (int jj = 0; jj < 2; ++jj) {
        gl_lds16(Kfb + (size_t)(st + 1) * 4096 + (idx + jj) * 512 + lane * 8, &Ks[buf ^ 1][idx + jj][0][0]);
        gl_lds16(Vfb + (size_t)(st + 1) * 4096 + (idx + jj) * 512 + lane * 8, &Vs[buf ^ 1][idx + jj][0][0]);
      }
    }
    const int s0 = st * 64;

    // load K/V frags for this step from LDS (shared by both tiles)
    f16x8 kf[8]; f16x8 vf[8];
    #pragma unroll
    for (int i = 0; i < 8; ++i) {
      kf[i] = *(const f16x8*)&Ks[buf][i][lane][0];
      vf[i] = *(const f16x8*)&Vs[buf][i][lane][0];
    }

    // ---- tile 1 ----
    if (st < e1) {
      f32x4 sc[4];
      #pragma unroll
      for (int ct = 0; ct < 4; ++ct) {
        f32x4 z = (f32x4){0.f, 0.f, 0.f, 0.f};
        z = MFMA32(kf[2 * ct], qa10, z);
        sc[ct] = MFMA32(kf[2 * ct + 1], qa11, z);
      }
      const bool domask = (s0 + 63) > (m1 + 1);
      f16x4 pa[4];
      #pragma unroll
      for (int ct = 0; ct < 4; ++ct)
        #pragma unroll
        for (int r = 0; r < 4; ++r) {
          float x = sc[ct][r];
          if (domask) {
            const int key = s0 + ct * 16 + quad * 4 + r;
            if (key > m1 + l16 + 1) x = -__builtin_inff();
          }
          const float pv = __builtin_amdgcn_exp2f(x);
          ls1 += pv;
          pa[ct][r] = (f16)pv;
        }
      #pragma unroll
      for (int ct = 0; ct < 4; ++ct)
        #pragma unroll
        for (int np = 0; np < 2; ++np) {
          f16x8 vv = vf[2 * ct + np];
          f16x4 blo = __builtin_shufflevector(vv, vv, 0, 1, 2, 3);
          f16x4 bhi = __builtin_shufflevector(vv, vv, 4, 5, 6, 7);
          o1[2 * np]     = MFMA16(pa[ct], blo, o1[2 * np]);
          o1[2 * np + 1] = MFMA16(pa[ct], bhi, o1[2 * np + 1]);
        }
    }

    // ---- tile 2 ----
    if (st < e2) {
      f32x4 sc[4];
      #pragma unroll
      for (int ct = 0; ct < 4; ++ct) {
        f32x4 z = (f32x4){0.f, 0.f, 0.f, 0.f};
        z = MFMA32(kf[2 * ct], qa20, z);
        sc[ct] = MFMA32(kf[2 * ct + 1], qa21, z);
      }
      const bool domask = (s0 + 63) > (m2 + 1);
      f16x4 pa[4];
      #pragma unroll
      for (int ct = 0; ct < 4; ++ct)
        #pragma unroll
        for (int r = 0; r < 4; ++r) {
          float x = sc[ct][r];
          if (domask) {
            const int key = s0 + ct * 16 + quad * 4 + r;
            if (key > m2 + l16 + 1) x = -__builtin_inff();
          }
          const float pv = __builtin_amdgcn_exp2f(x);
          ls2 += pv;
          pa[ct][r] = (f16)pv;
        }
      #pragma unroll
      for (int ct = 0; ct < 4; ++ct)
        #pragma unroll
        for (int np = 0; np < 2; ++np) {
          f16x8 vv = vf[2 * ct + np];
          f16x4 blo = __builtin_shufflevector(vv, vv, 0, 1, 2, 3);
          f16x4 bhi = __builtin_shufflevector(vv, vv, 4, 5, 6, 7);
          o2[2 * np]     = MFMA16(pa[ct], blo, o2[2 * np]);
          o2[2 * np + 1] = MFMA16(pa[ct], bhi, o2[2 * np + 1]);
        }
    }
  }

  // reduce l across quads; write partials (zero partials are valid)
  ls1 += __shfl_xor(ls1, 16, 64);
  ls1 += __shfl_xor(ls1, 32, 64);
  ls2 += __shfl_xor(ls2, 16, 64);
  ls2 += __shfl_xor(ls2, 32, 64);
  const size_t rbase = (size_t)(sp * BB + b) * TT;
  if (quad == 0) {
    lpart[rbase + m1 + l16] = ls1;
    lpart[rbase + m2 + l16] = ls2;
  }
  #pragma unroll
  for (int nt = 0; nt < 4; ++nt)
    #pragma unroll
    for (int r = 0; r < 4; ++r) {
      Opart[(rbase + m1 + quad * 4 + r) * HH + nt * 16 + l16] = o1[nt][r];
      Opart[(rbase + m2 + quad * 4 + r) * HH + nt * 16 + l16] = o2[nt][r];
    }
}

// ---------------------------------------------------------------------------
// Combine S split partials: out = sum_s O_s / sum_s l_s
// ---------------------------------------------------------------------------
__global__ __launch_bounds__(256) void combine_kernel(
    const float* __restrict__ Opart, const float* __restrict__ lpart,
    float* __restrict__ out, int S)
{
  const int idx = blockIdx.x * 256 + threadIdx.x;
  const int row = idx >> 4;
  const int c   = (idx & 15) * 4;
  float l = 0.f;
  f32x4 s = (f32x4){0.f, 0.f, 0.f, 0.f};
  for (int p = 0; p < S; ++p) {
    l += lpart[(size_t)p * BB * TT + row];
    s += *(const f32x4*)&Opart[((size_t)p * BB * TT + row) * HH + c];
  }
  const float inv = 1.0f / l;
  *(f32x4*)&out[(size_t)row * HH + c] = s * inv;
}

// ---------------------------------------------------------------------------
extern "C" void kernel_launch(void* const* d_in, const int* in_sizes, int n_in,
                              void* d_out, int out_size, void* d_ws, size_t ws_size,
                              hipStream_t stream)
{
  const float* q  = (const float*)d_in[0];
  const float* k  = (const float*)d_in[1];
  const float* v  = (const float*)d_in[2];
  const float* Wq = (const float*)d_in[3];
  const float* Wk = (const float*)d_in[4];
  const float* Wv = (const float*)d_in[5];
  float* out = (float*)d_out;

  const size_t n = (size_t)BB * TT * HH;   // 1,048,576 f16 per tensor
  const size_t need8 = (WF_ELEMS + 3 * n) * sizeof(f16)
                     + 8 * n * sizeof(float) + 8 * (size_t)BB * TT * sizeof(float);
  const int S = (ws_size >= need8) ? 8 : 4;

  f16* Wf = (f16*)d_ws;
  f16* Qf = Wf + WF_ELEMS;
  f16* Kf = Qf + n;
  f16* Vf = Kf + n;
  float* Opart = (float*)(Vf + n);
  float* lpart = Opart + (size_t)S * n;

  wrepack_kernel<<<dim3(384), 64, 0, stream>>>(Wq, Wk, Wv, Wf);
  proj_kernel<<<dim3(128, 3), 512, 0, stream>>>(q, k, v, Wf, Qf, Kf, Vf);
  attn_kernel<<<dim3(32, S, BB), 256, 0, stream>>>(Qf, Kf, Vf, Opart, lpart, S);
  combine_kernel<<<dim3(1024), 256, 0, stream>>>(Opart, lpart, out, S);
}